// Round 7
// baseline (603.413 us; speedup 1.0000x reference)
//
#include <hip/hip_runtime.h>

#define T_TOK 8192
#define DDIM 1024
#define IDIM 2048
#define NEXP 8

typedef short bf16x8 __attribute__((ext_vector_type(8)));
typedef float f32x4 __attribute__((ext_vector_type(4)));

__device__ __forceinline__ unsigned short f2bf(float f) {
  union { float f; unsigned int u; } v; v.f = f;
  unsigned int r = v.u + 0x7fffu + ((v.u >> 16) & 1u);
  return (unsigned short)(r >> 16);
}
__device__ __forceinline__ float bf2f(unsigned short u) {
  union { unsigned int u; float f; } v; v.u = (unsigned int)u << 16;
  return v.f;
}

typedef const __attribute__((address_space(1))) void* gas_t;
typedef __attribute__((address_space(3))) void* las_t;
__device__ __forceinline__ void async_copy16(void* lds, const void* g) {
  __builtin_amdgcn_global_load_lds((gas_t)g, (las_t)lds, 16, 0, 0);
}

// ---------------- transpose + convert via LDS: src[e][R][C] f32 -> dst[e][C'][R] bf16 ----------------
__global__ __launch_bounds__(256) void tconv_kernel(
    const float* __restrict__ src, ushort* __restrict__ dst, int R, int C,
    int sel, int interleave, size_t srcEStride, size_t dstEStride) {
  __shared__ ushort lt[64 * 72];
  const int e = blockIdx.z;
  const float* s = src + (size_t)e * srcEStride;
  ushort* d = dst + (size_t)e * dstEStride;
  const int c0 = blockIdx.x * 64, r0 = blockIdx.y * 64;
  const int t = threadIdx.x;
  const int tr = t >> 2;
  const int tc = (t & 3) * 16;
  const float* sp = s + (size_t)(r0 + tr) * C + c0 + tc;
  float4 v0 = ((const float4*)sp)[0];
  float4 v1 = ((const float4*)sp)[1];
  float4 v2 = ((const float4*)sp)[2];
  float4 v3 = ((const float4*)sp)[3];
#pragma unroll
  for (int j = 0; j < 4; ++j) lt[(tc + j) * 72 + tr]      = f2bf(((const float*)&v0)[j]);
#pragma unroll
  for (int j = 0; j < 4; ++j) lt[(tc + 4 + j) * 72 + tr]  = f2bf(((const float*)&v1)[j]);
#pragma unroll
  for (int j = 0; j < 4; ++j) lt[(tc + 8 + j) * 72 + tr]  = f2bf(((const float*)&v2)[j]);
#pragma unroll
  for (int j = 0; j < 4; ++j) lt[(tc + 12 + j) * 72 + tr] = f2bf(((const float*)&v3)[j]);
  __syncthreads();
  const int cr = t >> 2;
  const int seg = (t & 3) * 16;
  const int ci = c0 + cr;
  const int drow = interleave ? ((ci >> 6) * 128 + sel * 64 + (ci & 63)) : ci;
  uint4 o0 = *(const uint4*)&lt[cr * 72 + seg];
  uint4 o1 = *(const uint4*)&lt[cr * 72 + seg + 8];
  ushort* dp = d + (size_t)drow * R + r0 + seg;
  *(uint4*)dp = o0;
  *(uint4*)(dp + 8) = o1;
}

// ---------------- router: top-2 + expert lists, block-aggregated atomics; also emits xb (bf16 x) ----------------
__global__ __launch_bounds__(256) void router_kernel(
    const float* __restrict__ x, const float* __restrict__ rw, const float* __restrict__ rb,
    int* __restrict__ cnt, int* __restrict__ lists, float* __restrict__ wts,
    int* __restrict__ pexp, ushort* __restrict__ xb) {
  __shared__ int tokE[128];
  __shared__ int loc[128];
  __shared__ int hist[NEXP];
  __shared__ int base[NEXP];
  const int tid = threadIdx.x;
  const int w = tid >> 6, lane = tid & 63;
  if (tid < NEXP) hist[tid] = 0;
  __syncthreads();

#pragma unroll 1
  for (int tt = 0; tt < 16; ++tt) {
    const int token = blockIdx.x * 64 + w * 16 + tt;
    float acc[NEXP];
#pragma unroll
    for (int e = 0; e < NEXP; ++e) acc[e] = 0.f;
    const float* xr = x + (size_t)token * DDIM;
    ushort* xbr = xb + (size_t)token * DDIM;
#pragma unroll
    for (int j = 0; j < DDIM / 64; ++j) {
      int d = j * 64 + lane;
      float xv = xr[d];
      xbr[d] = f2bf(xv);  // fused convert (was its own kernel)
      const float4* wp = (const float4*)(rw + d * NEXP);
      float4 w0 = wp[0], w1 = wp[1];
      acc[0] += xv * w0.x; acc[1] += xv * w0.y; acc[2] += xv * w0.z; acc[3] += xv * w0.w;
      acc[4] += xv * w1.x; acc[5] += xv * w1.y; acc[6] += xv * w1.z; acc[7] += xv * w1.w;
    }
#pragma unroll
    for (int e = 0; e < NEXP; ++e) {
      float v = acc[e];
      for (int off = 32; off > 0; off >>= 1) v += __shfl_xor(v, off, 64);
      acc[e] = v;
    }
    if (lane == 0) {
      float l[NEXP];
#pragma unroll
      for (int e = 0; e < NEXP; ++e) l[e] = acc[e] + rb[e];
      int i0 = 0; float b0 = l[0];
#pragma unroll
      for (int e = 1; e < NEXP; ++e) if (l[e] > b0) { b0 = l[e]; i0 = e; }
      int i1 = -1; float b1 = -3.0e38f;
#pragma unroll
      for (int e = 0; e < NEXP; ++e) if (e != i0 && l[e] > b1) { b1 = l[e]; i1 = e; }
      float e1 = expf(b1 - b0);
      float inv = 1.f / (1.f + e1);
      wts[token * 2 + 0] = inv;
      wts[token * 2 + 1] = e1 * inv;
      pexp[token * 2 + 0] = i0;
      pexp[token * 2 + 1] = i1;
      const int k = (w * 16 + tt) * 2;
      tokE[k] = i0;
      tokE[k + 1] = i1;
      loc[k] = atomicAdd(&hist[i0], 1);
      loc[k + 1] = atomicAdd(&hist[i1], 1);
    }
  }
  __syncthreads();
  if (tid < NEXP) base[tid] = atomicAdd(&cnt[tid], hist[tid]);
  __syncthreads();
  if (tid < 128) {
    const int e = tokE[tid];
    const int token = blockIdx.x * 64 + (tid >> 1);
    lists[e * T_TOK + base[e] + loc[tid]] = token * 2 + (tid & 1);
  }
}

// ---------------- GEMM1: fused gate/up, 128x256 tile (A re-fetch 32x->16x), in-wave gate/up pairing ----------------
// by covers wcat rows [256by, 256by+256) = interleave groups g=2by(+waveN): gate cols nf0..3, up cols nf4..7
// live in the SAME wave -> no LDS epilogue exchange. XCD-chunked swizzle (nwg=1024, chunk=128).
__global__ __launch_bounds__(256, 2) void gemm1_kernel(
    const ushort* __restrict__ xb, const ushort* __restrict__ wcat,
    const float* __restrict__ gate_b, const float* __restrict__ up_b,
    const int* __restrict__ lists, const int* __restrict__ cnt,
    ushort* __restrict__ hbuf) {
  const int e = blockIdx.z;
  const int ce = cnt[e];
  // grid: x = 64 (m0 slots), y = 16 (by). nwg = 1024, chunk = 128.
  const int p = blockIdx.x + (blockIdx.y << 6);
  const int l = (p & 7) * 128 + (p >> 3);
  const int m0 = (l & 63) * 128;
  const int by = l >> 6;  // 0..15
  if (m0 >= ce) return;

  __shared__ __align__(16) ushort smem[128 * 64 + 256 * 64];  // As 16KB | Bs 32KB
  __shared__ int rowinfo[128];
  ushort* As = smem;
  ushort* Bs = smem + 128 * 64;

  const int tid = threadIdx.x;
  if (tid < 128) {
    int slot = m0 + tid;
    rowinfo[tid] = lists[e * T_TOK + (slot < ce ? slot : 0)];
  }
  __syncthreads();

  const int w = tid >> 6, lane = tid & 63;
  const int fm = lane & 15, fq = lane >> 4;
  const int waveM = w >> 1, waveN = w & 1;
  const int lr = lane >> 3;
  const int lchunk = ((lane & 7) ^ lr) * 8;

  const ushort* wcatE = wcat + (size_t)e * 4096 * 1024;
  const ushort* aG[4]; const ushort* bG[8];
  ushort* aL[4]; ushort* bL[8];
#pragma unroll
  for (int j = 0; j < 4; ++j) {
    int rl = 32 * w + 8 * j + lr;
    aG[j] = xb + (size_t)(rowinfo[rl] >> 1) * DDIM + lchunk;
    aL[j] = As + (32 * w + 8 * j) * 64;
  }
#pragma unroll
  for (int j = 0; j < 8; ++j) {
    int rl = 64 * w + 8 * j + lr;
    bG[j] = wcatE + (size_t)(256 * by + rl) * DDIM + lchunk;
    bL[j] = Bs + (64 * w + 8 * j) * 64;
  }

  f32x4 acc[4][8];
  const f32x4 zero4 = {0.f, 0.f, 0.f, 0.f};
#pragma unroll
  for (int i = 0; i < 4; ++i)
#pragma unroll
    for (int j = 0; j < 8; ++j) acc[i][j] = zero4;

#pragma unroll 1
  for (int kt = 0; kt < DDIM / 64; ++kt) {
    __syncthreads();
#pragma unroll
    for (int j = 0; j < 4; ++j) async_copy16(aL[j], aG[j] + kt * 64);
#pragma unroll
    for (int j = 0; j < 8; ++j) async_copy16(bL[j], bG[j] + kt * 64);
    __syncthreads();
#pragma unroll
    for (int ks = 0; ks < 2; ++ks) {
      bf16x8 af[4], bfr[8];
#pragma unroll
      for (int mf = 0; mf < 4; ++mf) {
        int row = 64 * waveM + 16 * mf + fm;
        af[mf] = *(const bf16x8*)&As[row * 64 + (((ks * 4 + fq) ^ (fm & 7)) * 8)];
      }
#pragma unroll
      for (int nf = 0; nf < 8; ++nf) {
        int row = 128 * waveN + 16 * nf + fm;
        bfr[nf] = *(const bf16x8*)&Bs[row * 64 + (((ks * 4 + fq) ^ (fm & 7)) * 8)];
      }
#pragma unroll
      for (int mf = 0; mf < 4; ++mf)
#pragma unroll
        for (int nf = 0; nf < 8; ++nf)
          acc[mf][nf] = __builtin_amdgcn_mfma_f32_16x16x32_bf16(af[mf], bfr[nf], acc[mf][nf], 0, 0, 0);
    }
  }

  // epilogue: gate (nf<4) and up (nf+4) are in the same wave -> direct silu(g)*u, no LDS
  const int g_group = 2 * by + waveN;  // 0..31, output cols 64*g_group..+63
#pragma unroll
  for (int mf = 0; mf < 4; ++mf) {
#pragma unroll
    for (int r = 0; r < 4; ++r) {
      const int row = 64 * waveM + 16 * mf + 4 * fq + r;
      if (m0 + row < ce) {
        const int packed = rowinfo[row];
#pragma unroll
        for (int nf = 0; nf < 4; ++nf) {
          const int col = 64 * g_group + 16 * nf + fm;
          float g = acc[mf][nf][r] + gate_b[e * IDIM + col];
          float u = acc[mf][nf + 4][r] + up_b[e * IDIM + col];
          float h = g * (1.f / (1.f + __expf(-g))) * u;
          hbuf[(size_t)packed * IDIM + col] = f2bf(h);
        }
      }
    }
  }
}

// ---------------- GEMM2: cbuf[pair] = h @ down_w, 128x256 tile (A re-fetch 8x->4x) ----------------
__global__ __launch_bounds__(256, 2) void gemm2_kernel(
    const ushort* __restrict__ hbuf, const ushort* __restrict__ downT,
    const int* __restrict__ lists, const int* __restrict__ cnt,
    ushort* __restrict__ cbuf) {
  const int e = blockIdx.z;
  const int ce = cnt[e];
  // grid: x = 64 (m0 slots), y = 4 (by). nwg = 256, chunk = 32.
  const int p = blockIdx.x + (blockIdx.y << 6);
  const int l = (p & 7) * 32 + (p >> 3);
  const int m0 = (l & 63) * 128;
  const int by = l >> 6;  // 0..3 -> cols 256*by..
  if (m0 >= ce) return;

  __shared__ __align__(16) ushort smem[128 * 64 + 256 * 64];
  __shared__ int rowinfo[128];
  ushort* As = smem;
  ushort* Bs = smem + 128 * 64;

  const int tid = threadIdx.x;
  if (tid < 128) {
    int slot = m0 + tid;
    rowinfo[tid] = lists[e * T_TOK + (slot < ce ? slot : 0)];
  }
  __syncthreads();

  const int w = tid >> 6, lane = tid & 63;
  const int fm = lane & 15, fq = lane >> 4;
  const int waveM = w >> 1, waveN = w & 1;
  const int lr = lane >> 3;
  const int lchunk = ((lane & 7) ^ lr) * 8;

  const ushort* downE = downT + (size_t)e * DDIM * IDIM;
  const ushort* aG[4]; const ushort* bG[8];
  ushort* aL[4]; ushort* bL[8];
#pragma unroll
  for (int j = 0; j < 4; ++j) {
    int rl = 32 * w + 8 * j + lr;
    aG[j] = hbuf + (size_t)rowinfo[rl] * IDIM + lchunk;
    aL[j] = As + (32 * w + 8 * j) * 64;
  }
#pragma unroll
  for (int j = 0; j < 8; ++j) {
    int rl = 64 * w + 8 * j + lr;
    bG[j] = downE + (size_t)(256 * by + rl) * IDIM + lchunk;
    bL[j] = Bs + (64 * w + 8 * j) * 64;
  }

  f32x4 acc[4][8];
  const f32x4 zero4 = {0.f, 0.f, 0.f, 0.f};
#pragma unroll
  for (int i = 0; i < 4; ++i)
#pragma unroll
    for (int j = 0; j < 8; ++j) acc[i][j] = zero4;

#pragma unroll 1
  for (int kt = 0; kt < IDIM / 64; ++kt) {
    __syncthreads();
#pragma unroll
    for (int j = 0; j < 4; ++j) async_copy16(aL[j], aG[j] + kt * 64);
#pragma unroll
    for (int j = 0; j < 8; ++j) async_copy16(bL[j], bG[j] + kt * 64);
    __syncthreads();
#pragma unroll
    for (int ks = 0; ks < 2; ++ks) {
      bf16x8 af[4], bfr[8];
#pragma unroll
      for (int mf = 0; mf < 4; ++mf) {
        int row = 64 * waveM + 16 * mf + fm;
        af[mf] = *(const bf16x8*)&As[row * 64 + (((ks * 4 + fq) ^ (fm & 7)) * 8)];
      }
#pragma unroll
      for (int nf = 0; nf < 8; ++nf) {
        int row = 128 * waveN + 16 * nf + fm;
        bfr[nf] = *(const bf16x8*)&Bs[row * 64 + (((ks * 4 + fq) ^ (fm & 7)) * 8)];
      }
#pragma unroll
      for (int mf = 0; mf < 4; ++mf)
#pragma unroll
        for (int nf = 0; nf < 8; ++nf)
          acc[mf][nf] = __builtin_amdgcn_mfma_f32_16x16x32_bf16(af[mf], bfr[nf], acc[mf][nf], 0, 0, 0);
    }
  }

#pragma unroll
  for (int mf = 0; mf < 4; ++mf) {
#pragma unroll
    for (int r = 0; r < 4; ++r) {
      const int row = 64 * waveM + 16 * mf + 4 * fq + r;
      if (m0 + row < ce) {
        const int packed = rowinfo[row];
        ushort* crow = cbuf + (size_t)packed * DDIM + 256 * by + 128 * waveN;
#pragma unroll
        for (int nf = 0; nf < 8; ++nf)
          crow[16 * nf + fm] = f2bf(acc[mf][nf][r]);
      }
    }
  }
}

// ---------------- combine: out[t] = w0*(c0+db[e0]) + w1*(c1+db[e1]) ----------------
__global__ __launch_bounds__(256) void combine_kernel(
    const ushort* __restrict__ cbuf, const float* __restrict__ down_b,
    const int* __restrict__ pexp, const float* __restrict__ wts,
    float* __restrict__ out) {
  const int i = blockIdx.x * 256 + threadIdx.x;  // one thread per 8 cols
  const int token = i >> 7;                      // DDIM/8 = 128 segs
  const int seg = (i & 127) * 8;
  const float w0 = wts[token * 2], w1 = wts[token * 2 + 1];
  const int e0 = pexp[token * 2], e1 = pexp[token * 2 + 1];
  const ushort* c0 = cbuf + (size_t)(token * 2) * DDIM + seg;
  const ushort* c1 = c0 + DDIM;
  const float* b0 = down_b + e0 * DDIM + seg;
  const float* b1 = down_b + e1 * DDIM + seg;
  ushort4 v0a = ((const ushort4*)c0)[0], v0b = ((const ushort4*)c0)[1];
  ushort4 v1a = ((const ushort4*)c1)[0], v1b = ((const ushort4*)c1)[1];
  float4 ba0 = ((const float4*)b0)[0], bb0 = ((const float4*)b0)[1];
  float4 ba1 = ((const float4*)b1)[0], bb1 = ((const float4*)b1)[1];
  float4 o0, o1;
  o0.x = w0 * (bf2f(v0a.x) + ba0.x) + w1 * (bf2f(v1a.x) + ba1.x);
  o0.y = w0 * (bf2f(v0a.y) + ba0.y) + w1 * (bf2f(v1a.y) + ba1.y);
  o0.z = w0 * (bf2f(v0a.z) + ba0.z) + w1 * (bf2f(v1a.z) + ba1.z);
  o0.w = w0 * (bf2f(v0a.w) + ba0.w) + w1 * (bf2f(v1a.w) + ba1.w);
  o1.x = w0 * (bf2f(v0b.x) + bb0.x) + w1 * (bf2f(v1b.x) + bb1.x);
  o1.y = w0 * (bf2f(v0b.y) + bb0.y) + w1 * (bf2f(v1b.y) + bb1.y);
  o1.z = w0 * (bf2f(v0b.z) + bb0.z) + w1 * (bf2f(v1b.z) + bb1.z);
  o1.w = w0 * (bf2f(v0b.w) + bb0.w) + w1 * (bf2f(v1b.w) + bb1.w);
  float* op = out + (size_t)token * DDIM + seg;
  ((float4*)op)[0] = o0;
  ((float4*)op)[1] = o1;
}

extern "C" void kernel_launch(void* const* d_in, const int* in_sizes, int n_in,
                              void* d_out, int out_size, void* d_ws, size_t ws_size,
                              hipStream_t stream) {
  const float* x = (const float*)d_in[0];
  const float* rw = (const float*)d_in[1];
  const float* rb = (const float*)d_in[2];
  const float* gw = (const float*)d_in[3];
  const float* gb = (const float*)d_in[4];
  const float* uw = (const float*)d_in[5];
  const float* ub = (const float*)d_in[6];
  const float* dw = (const float*)d_in[7];
  const float* db = (const float*)d_in[8];
  float* out = (float*)d_out;

  char* ws = (char*)d_ws;
  ushort* xb    = (ushort*)(ws);                              // 16 MB
  ushort* hbuf  = (ushort*)(ws + (16ull << 20));              // 64 MB
  ushort* wcat  = (ushort*)(ws + (80ull << 20));              // 64 MB (dead after gemm1)
  ushort* cbuf  = wcat;                                       // 32 MB, aliases wcat
  ushort* downT = (ushort*)(ws + (144ull << 20));             // 32 MB
  float*  wts   = (float*) (ws + (176ull << 20));             // 64 KB
  int*    lists = (int*)   (ws + (176ull << 20) + 65536);     // 256 KB
  int*    cnt   = (int*)   (ws + (176ull << 20) + 65536 + 262144);
  int*    pexp  = (int*)   (ws + (176ull << 20) + 65536 + 262144 + 4096);  // 64 KB

  hipMemsetAsync(cnt, 0, NEXP * sizeof(int), stream);

  router_kernel<<<T_TOK / 64, 256, 0, stream>>>(x, rw, rb, cnt, lists, wts, pexp, xb);
  tconv_kernel<<<dim3(IDIM / 64, DDIM / 64, NEXP), 256, 0, stream>>>(
      gw, wcat, DDIM, IDIM, 0, 1, (size_t)DDIM * IDIM, (size_t)2 * IDIM * DDIM);
  tconv_kernel<<<dim3(IDIM / 64, DDIM / 64, NEXP), 256, 0, stream>>>(
      uw, wcat, DDIM, IDIM, 1, 1, (size_t)DDIM * IDIM, (size_t)2 * IDIM * DDIM);
  tconv_kernel<<<dim3(DDIM / 64, IDIM / 64, NEXP), 256, 0, stream>>>(
      dw, downT, IDIM, DDIM, 0, 0, (size_t)IDIM * DDIM, (size_t)DDIM * IDIM);

  gemm1_kernel<<<dim3(T_TOK / 128, IDIM / 128, NEXP), 256, 0, stream>>>(
      xb, wcat, gb, ub, lists, cnt, hbuf);
  gemm2_kernel<<<dim3(T_TOK / 128, DDIM / 256, NEXP), 256, 0, stream>>>(
      hbuf, downT, lists, cnt, cbuf);
  combine_kernel<<<T_TOK * DDIM / 8 / 256, 256, 0, stream>>>(cbuf, db, pexp, wts, out);
}

// Round 8
// 577.090 us; speedup vs baseline: 1.0456x; 1.0456x over previous
//
#include <hip/hip_runtime.h>

#define T_TOK 8192
#define DDIM 1024
#define IDIM 2048
#define NEXP 8

typedef short bf16x8 __attribute__((ext_vector_type(8)));
typedef float f32x4 __attribute__((ext_vector_type(4)));

__device__ __forceinline__ unsigned short f2bf(float f) {
  union { float f; unsigned int u; } v; v.f = f;
  unsigned int r = v.u + 0x7fffu + ((v.u >> 16) & 1u);
  return (unsigned short)(r >> 16);
}
__device__ __forceinline__ float bf2f(unsigned short u) {
  union { unsigned int u; float f; } v; v.u = (unsigned int)u << 16;
  return v.f;
}

typedef const __attribute__((address_space(1))) void* gas_t;
typedef __attribute__((address_space(3))) void* las_t;
__device__ __forceinline__ void async_copy16(void* lds, const void* g) {
  __builtin_amdgcn_global_load_lds((gas_t)g, (las_t)lds, 16, 0, 0);
}

// ---------------- transpose + convert via LDS: src[e][R][C] f32 -> dst[e][C'][R] bf16 ----------------
__global__ __launch_bounds__(256) void tconv_kernel(
    const float* __restrict__ src, ushort* __restrict__ dst, int R, int C,
    int sel, int interleave, size_t srcEStride, size_t dstEStride) {
  __shared__ ushort lt[64 * 72];
  const int e = blockIdx.z;
  const float* s = src + (size_t)e * srcEStride;
  ushort* d = dst + (size_t)e * dstEStride;
  const int c0 = blockIdx.x * 64, r0 = blockIdx.y * 64;
  const int t = threadIdx.x;
  const int tr = t >> 2;
  const int tc = (t & 3) * 16;
  const float* sp = s + (size_t)(r0 + tr) * C + c0 + tc;
  float4 v0 = ((const float4*)sp)[0];
  float4 v1 = ((const float4*)sp)[1];
  float4 v2 = ((const float4*)sp)[2];
  float4 v3 = ((const float4*)sp)[3];
#pragma unroll
  for (int j = 0; j < 4; ++j) lt[(tc + j) * 72 + tr]      = f2bf(((const float*)&v0)[j]);
#pragma unroll
  for (int j = 0; j < 4; ++j) lt[(tc + 4 + j) * 72 + tr]  = f2bf(((const float*)&v1)[j]);
#pragma unroll
  for (int j = 0; j < 4; ++j) lt[(tc + 8 + j) * 72 + tr]  = f2bf(((const float*)&v2)[j]);
#pragma unroll
  for (int j = 0; j < 4; ++j) lt[(tc + 12 + j) * 72 + tr] = f2bf(((const float*)&v3)[j]);
  __syncthreads();
  const int cr = t >> 2;
  const int seg = (t & 3) * 16;
  const int ci = c0 + cr;
  const int drow = interleave ? ((ci >> 6) * 128 + sel * 64 + (ci & 63)) : ci;
  uint4 o0 = *(const uint4*)&lt[cr * 72 + seg];
  uint4 o1 = *(const uint4*)&lt[cr * 72 + seg + 8];
  ushort* dp = d + (size_t)drow * R + r0 + seg;
  *(uint4*)dp = o0;
  *(uint4*)(dp + 8) = o1;
}

// ---------------- router: top-2 + expert lists, block-aggregated atomics; also emits xb (bf16 x) ----------------
__global__ __launch_bounds__(256) void router_kernel(
    const float* __restrict__ x, const float* __restrict__ rw, const float* __restrict__ rb,
    int* __restrict__ cnt, int* __restrict__ lists, float* __restrict__ wts,
    int* __restrict__ pexp, ushort* __restrict__ xb) {
  __shared__ int tokE[128];
  __shared__ int loc[128];
  __shared__ int hist[NEXP];
  __shared__ int base[NEXP];
  const int tid = threadIdx.x;
  const int w = tid >> 6, lane = tid & 63;
  if (tid < NEXP) hist[tid] = 0;
  __syncthreads();

#pragma unroll 1
  for (int tt = 0; tt < 16; ++tt) {
    const int token = blockIdx.x * 64 + w * 16 + tt;
    float acc[NEXP];
#pragma unroll
    for (int e = 0; e < NEXP; ++e) acc[e] = 0.f;
    const float* xr = x + (size_t)token * DDIM;
    ushort* xbr = xb + (size_t)token * DDIM;
#pragma unroll
    for (int j = 0; j < DDIM / 64; ++j) {
      int d = j * 64 + lane;
      float xv = xr[d];
      xbr[d] = f2bf(xv);  // fused convert
      const float4* wp = (const float4*)(rw + d * NEXP);
      float4 w0 = wp[0], w1 = wp[1];
      acc[0] += xv * w0.x; acc[1] += xv * w0.y; acc[2] += xv * w0.z; acc[3] += xv * w0.w;
      acc[4] += xv * w1.x; acc[5] += xv * w1.y; acc[6] += xv * w1.z; acc[7] += xv * w1.w;
    }
#pragma unroll
    for (int e = 0; e < NEXP; ++e) {
      float v = acc[e];
      for (int off = 32; off > 0; off >>= 1) v += __shfl_xor(v, off, 64);
      acc[e] = v;
    }
    if (lane == 0) {
      float l[NEXP];
#pragma unroll
      for (int e = 0; e < NEXP; ++e) l[e] = acc[e] + rb[e];
      int i0 = 0; float b0 = l[0];
#pragma unroll
      for (int e = 1; e < NEXP; ++e) if (l[e] > b0) { b0 = l[e]; i0 = e; }
      int i1 = -1; float b1 = -3.0e38f;
#pragma unroll
      for (int e = 0; e < NEXP; ++e) if (e != i0 && l[e] > b1) { b1 = l[e]; i1 = e; }
      float e1 = expf(b1 - b0);
      float inv = 1.f / (1.f + e1);
      wts[token * 2 + 0] = inv;
      wts[token * 2 + 1] = e1 * inv;
      pexp[token * 2 + 0] = i0;
      pexp[token * 2 + 1] = i1;
      const int k = (w * 16 + tt) * 2;
      tokE[k] = i0;
      tokE[k + 1] = i1;
      loc[k] = atomicAdd(&hist[i0], 1);
      loc[k + 1] = atomicAdd(&hist[i1], 1);
    }
  }
  __syncthreads();
  if (tid < NEXP) base[tid] = atomicAdd(&cnt[tid], hist[tid]);
  __syncthreads();
  if (tid < 128) {
    const int e = tokE[tid];
    const int token = blockIdx.x * 64 + (tid >> 1);
    lists[e * T_TOK + base[e] + loc[tid]] = token * 2 + (tid & 1);
  }
}

// ---------------- GEMM1: 256x(128 wcat rows) tile, waves split by M only ----------------
// Each wave owns 64 rows x all 128 B-rows: 12 ds_read per ks for 32 MFMA (ratio 2.67 vs 2.0)
// -> relieves LDS-read critical path (R6/R7 analysis). by = one full gate/up interleave group
// -> gate (nf 0-3) and up (nf 4-7) in SAME wave: direct silu fuse, no LDS epilogue.
// LDS 48KB -> 3 blocks/CU. XCD-chunked swizzle (nwg=1024/expert, chunk=128).
__global__ __launch_bounds__(256, 2) void gemm1_kernel(
    const ushort* __restrict__ xb, const ushort* __restrict__ wcat,
    const float* __restrict__ gate_b, const float* __restrict__ up_b,
    const int* __restrict__ lists, const int* __restrict__ cnt,
    ushort* __restrict__ hbuf) {
  const int e = blockIdx.z;
  const int ce = cnt[e];
  // grid: x = 32 (m0 slots of 256 rows), y = 32 (by groups). nwg = 1024, chunk = 128.
  const int p = blockIdx.x + (blockIdx.y << 5);
  const int l = (p & 7) * 128 + (p >> 3);
  const int m0 = (l & 31) * 256;
  const int by = l >> 5;  // 0..31: wcat rows [128by,128by+128) = gate+up of output cols [64by,64by+64)
  if (m0 >= ce) return;

  __shared__ __align__(16) ushort smem[256 * 64 + 128 * 64];  // As 32KB | Bs 16KB
  __shared__ int rowinfo[256];
  ushort* As = smem;
  ushort* Bs = smem + 256 * 64;

  const int tid = threadIdx.x;
  {
    int slot = m0 + tid;
    rowinfo[tid] = lists[e * T_TOK + (slot < ce ? slot : 0)];
  }
  __syncthreads();

  const int w = tid >> 6, lane = tid & 63;
  const int fm = lane & 15, fq = lane >> 4;
  const int lr = lane >> 3;
  const int lchunk = ((lane & 7) ^ lr) * 8;

  const ushort* wcatE = wcat + (size_t)e * 4096 * 1024;
  const ushort* aG[8]; const ushort* bG[4];
  ushort* aL[8]; ushort* bL[4];
#pragma unroll
  for (int j = 0; j < 8; ++j) {
    int rl = 64 * w + 8 * j + lr;               // 0..255
    aG[j] = xb + (size_t)(rowinfo[rl] >> 1) * DDIM + lchunk;
    aL[j] = As + (64 * w + 8 * j) * 64;
  }
#pragma unroll
  for (int j = 0; j < 4; ++j) {
    int rl = 32 * w + 8 * j + lr;               // 0..127
    bG[j] = wcatE + (size_t)(128 * by + rl) * DDIM + lchunk;
    bL[j] = Bs + (32 * w + 8 * j) * 64;
  }

  f32x4 acc[4][8];
  const f32x4 zero4 = {0.f, 0.f, 0.f, 0.f};
#pragma unroll
  for (int i = 0; i < 4; ++i)
#pragma unroll
    for (int j = 0; j < 8; ++j) acc[i][j] = zero4;

#pragma unroll 1
  for (int kt = 0; kt < DDIM / 64; ++kt) {
    __syncthreads();
#pragma unroll
    for (int j = 0; j < 8; ++j) async_copy16(aL[j], aG[j] + kt * 64);
#pragma unroll
    for (int j = 0; j < 4; ++j) async_copy16(bL[j], bG[j] + kt * 64);
    __syncthreads();
#pragma unroll
    for (int ks = 0; ks < 2; ++ks) {
      bf16x8 af[4], bfr[8];
#pragma unroll
      for (int mf = 0; mf < 4; ++mf) {
        int row = 64 * w + 16 * mf + fm;        // wave's own 64 rows
        af[mf] = *(const bf16x8*)&As[row * 64 + (((ks * 4 + fq) ^ (fm & 7)) * 8)];
      }
#pragma unroll
      for (int nf = 0; nf < 8; ++nf) {
        int row = 16 * nf + fm;                 // all 128 B rows (shared across waves)
        bfr[nf] = *(const bf16x8*)&Bs[row * 64 + (((ks * 4 + fq) ^ (fm & 7)) * 8)];
      }
#pragma unroll
      for (int mf = 0; mf < 4; ++mf)
#pragma unroll
        for (int nf = 0; nf < 8; ++nf)
          acc[mf][nf] = __builtin_amdgcn_mfma_f32_16x16x32_bf16(af[mf], bfr[nf], acc[mf][nf], 0, 0, 0);
    }
  }

  // epilogue: gate rows (B 0-63 -> nf 0-3) and up rows (B 64-127 -> nf 4-7), same cols
#pragma unroll
  for (int mf = 0; mf < 4; ++mf) {
#pragma unroll
    for (int r = 0; r < 4; ++r) {
      const int row = 64 * w + 16 * mf + 4 * fq + r;
      if (m0 + row < ce) {
        const int packed = rowinfo[row];
#pragma unroll
        for (int nf = 0; nf < 4; ++nf) {
          const int col = 64 * by + 16 * nf + fm;
          float g = acc[mf][nf][r] + gate_b[e * IDIM + col];
          float u = acc[mf][nf + 4][r] + up_b[e * IDIM + col];
          float h = g * (1.f / (1.f + __expf(-g))) * u;
          hbuf[(size_t)packed * IDIM + col] = f2bf(h);
        }
      }
    }
  }
}

// ---------------- GEMM2: 256x128 tile, waves split by M only, K=2048 ----------------
__global__ __launch_bounds__(256, 2) void gemm2_kernel(
    const ushort* __restrict__ hbuf, const ushort* __restrict__ downT,
    const int* __restrict__ lists, const int* __restrict__ cnt,
    ushort* __restrict__ cbuf) {
  const int e = blockIdx.z;
  const int ce = cnt[e];
  // grid: x = 32 (m0 slots of 256 rows), y = 8 (by). nwg = 256, chunk = 32.
  const int p = blockIdx.x + (blockIdx.y << 5);
  const int l = (p & 7) * 32 + (p >> 3);
  const int m0 = (l & 31) * 256;
  const int by = l >> 5;  // 0..7 -> output cols 128*by..
  if (m0 >= ce) return;

  __shared__ __align__(16) ushort smem[256 * 64 + 128 * 64];
  __shared__ int rowinfo[256];
  ushort* As = smem;
  ushort* Bs = smem + 256 * 64;

  const int tid = threadIdx.x;
  {
    int slot = m0 + tid;
    rowinfo[tid] = lists[e * T_TOK + (slot < ce ? slot : 0)];
  }
  __syncthreads();

  const int w = tid >> 6, lane = tid & 63;
  const int fm = lane & 15, fq = lane >> 4;
  const int lr = lane >> 3;
  const int lchunk = ((lane & 7) ^ lr) * 8;

  const ushort* downE = downT + (size_t)e * DDIM * IDIM;
  const ushort* aG[8]; const ushort* bG[4];
  ushort* aL[8]; ushort* bL[4];
#pragma unroll
  for (int j = 0; j < 8; ++j) {
    int rl = 64 * w + 8 * j + lr;
    aG[j] = hbuf + (size_t)rowinfo[rl] * IDIM + lchunk;
    aL[j] = As + (64 * w + 8 * j) * 64;
  }
#pragma unroll
  for (int j = 0; j < 4; ++j) {
    int rl = 32 * w + 8 * j + lr;
    bG[j] = downE + (size_t)(128 * by + rl) * IDIM + lchunk;
    bL[j] = Bs + (32 * w + 8 * j) * 64;
  }

  f32x4 acc[4][8];
  const f32x4 zero4 = {0.f, 0.f, 0.f, 0.f};
#pragma unroll
  for (int i = 0; i < 4; ++i)
#pragma unroll
    for (int j = 0; j < 8; ++j) acc[i][j] = zero4;

#pragma unroll 1
  for (int kt = 0; kt < IDIM / 64; ++kt) {
    __syncthreads();
#pragma unroll
    for (int j = 0; j < 8; ++j) async_copy16(aL[j], aG[j] + kt * 64);
#pragma unroll
    for (int j = 0; j < 4; ++j) async_copy16(bL[j], bG[j] + kt * 64);
    __syncthreads();
#pragma unroll
    for (int ks = 0; ks < 2; ++ks) {
      bf16x8 af[4], bfr[8];
#pragma unroll
      for (int mf = 0; mf < 4; ++mf) {
        int row = 64 * w + 16 * mf + fm;
        af[mf] = *(const bf16x8*)&As[row * 64 + (((ks * 4 + fq) ^ (fm & 7)) * 8)];
      }
#pragma unroll
      for (int nf = 0; nf < 8; ++nf) {
        int row = 16 * nf + fm;
        bfr[nf] = *(const bf16x8*)&Bs[row * 64 + (((ks * 4 + fq) ^ (fm & 7)) * 8)];
      }
#pragma unroll
      for (int mf = 0; mf < 4; ++mf)
#pragma unroll
        for (int nf = 0; nf < 8; ++nf)
          acc[mf][nf] = __builtin_amdgcn_mfma_f32_16x16x32_bf16(af[mf], bfr[nf], acc[mf][nf], 0, 0, 0);
    }
  }

#pragma unroll
  for (int mf = 0; mf < 4; ++mf) {
#pragma unroll
    for (int r = 0; r < 4; ++r) {
      const int row = 64 * w + 16 * mf + 4 * fq + r;
      if (m0 + row < ce) {
        const int packed = rowinfo[row];
        ushort* crow = cbuf + (size_t)packed * DDIM + 128 * by;
#pragma unroll
        for (int nf = 0; nf < 8; ++nf)
          crow[16 * nf + fm] = f2bf(acc[mf][nf][r]);
      }
    }
  }
}

// ---------------- combine: out[t] = w0*(c0+db[e0]) + w1*(c1+db[e1]) ----------------
__global__ __launch_bounds__(256) void combine_kernel(
    const ushort* __restrict__ cbuf, const float* __restrict__ down_b,
    const int* __restrict__ pexp, const float* __restrict__ wts,
    float* __restrict__ out) {
  const int i = blockIdx.x * 256 + threadIdx.x;  // one thread per 8 cols
  const int token = i >> 7;                      // DDIM/8 = 128 segs
  const int seg = (i & 127) * 8;
  const float w0 = wts[token * 2], w1 = wts[token * 2 + 1];
  const int e0 = pexp[token * 2], e1 = pexp[token * 2 + 1];
  const ushort* c0 = cbuf + (size_t)(token * 2) * DDIM + seg;
  const ushort* c1 = c0 + DDIM;
  const float* b0 = down_b + e0 * DDIM + seg;
  const float* b1 = down_b + e1 * DDIM + seg;
  ushort4 v0a = ((const ushort4*)c0)[0], v0b = ((const ushort4*)c0)[1];
  ushort4 v1a = ((const ushort4*)c1)[0], v1b = ((const ushort4*)c1)[1];
  float4 ba0 = ((const float4*)b0)[0], bb0 = ((const float4*)b0)[1];
  float4 ba1 = ((const float4*)b1)[0], bb1 = ((const float4*)b1)[1];
  float4 o0, o1;
  o0.x = w0 * (bf2f(v0a.x) + ba0.x) + w1 * (bf2f(v1a.x) + ba1.x);
  o0.y = w0 * (bf2f(v0a.y) + ba0.y) + w1 * (bf2f(v1a.y) + ba1.y);
  o0.z = w0 * (bf2f(v0a.z) + ba0.z) + w1 * (bf2f(v1a.z) + ba1.z);
  o0.w = w0 * (bf2f(v0a.w) + ba0.w) + w1 * (bf2f(v1a.w) + ba1.w);
  o1.x = w0 * (bf2f(v0b.x) + bb0.x) + w1 * (bf2f(v1b.x) + bb1.x);
  o1.y = w0 * (bf2f(v0b.y) + bb0.y) + w1 * (bf2f(v1b.y) + bb1.y);
  o1.z = w0 * (bf2f(v0b.z) + bb0.z) + w1 * (bf2f(v1b.z) + bb1.z);
  o1.w = w0 * (bf2f(v0b.w) + bb0.w) + w1 * (bf2f(v1b.w) + bb1.w);
  float* op = out + (size_t)token * DDIM + seg;
  ((float4*)op)[0] = o0;
  ((float4*)op)[1] = o1;
}

extern "C" void kernel_launch(void* const* d_in, const int* in_sizes, int n_in,
                              void* d_out, int out_size, void* d_ws, size_t ws_size,
                              hipStream_t stream) {
  const float* x = (const float*)d_in[0];
  const float* rw = (const float*)d_in[1];
  const float* rb = (const float*)d_in[2];
  const float* gw = (const float*)d_in[3];
  const float* gb = (const float*)d_in[4];
  const float* uw = (const float*)d_in[5];
  const float* ub = (const float*)d_in[6];
  const float* dw = (const float*)d_in[7];
  const float* db = (const float*)d_in[8];
  float* out = (float*)d_out;

  char* ws = (char*)d_ws;
  ushort* xb    = (ushort*)(ws);                              // 16 MB
  ushort* hbuf  = (ushort*)(ws + (16ull << 20));              // 64 MB
  ushort* wcat  = (ushort*)(ws + (80ull << 20));              // 64 MB (dead after gemm1)
  ushort* cbuf  = wcat;                                       // 32 MB, aliases wcat
  ushort* downT = (ushort*)(ws + (144ull << 20));             // 32 MB
  float*  wts   = (float*) (ws + (176ull << 20));             // 64 KB
  int*    lists = (int*)   (ws + (176ull << 20) + 65536);     // 256 KB
  int*    cnt   = (int*)   (ws + (176ull << 20) + 65536 + 262144);
  int*    pexp  = (int*)   (ws + (176ull << 20) + 65536 + 262144 + 4096);  // 64 KB

  hipMemsetAsync(cnt, 0, NEXP * sizeof(int), stream);

  router_kernel<<<T_TOK / 64, 256, 0, stream>>>(x, rw, rb, cnt, lists, wts, pexp, xb);
  tconv_kernel<<<dim3(IDIM / 64, DDIM / 64, NEXP), 256, 0, stream>>>(
      gw, wcat, DDIM, IDIM, 0, 1, (size_t)DDIM * IDIM, (size_t)2 * IDIM * DDIM);
  tconv_kernel<<<dim3(IDIM / 64, DDIM / 64, NEXP), 256, 0, stream>>>(
      uw, wcat, DDIM, IDIM, 1, 1, (size_t)DDIM * IDIM, (size_t)2 * IDIM * DDIM);
  tconv_kernel<<<dim3(DDIM / 64, IDIM / 64, NEXP), 256, 0, stream>>>(
      dw, downT, IDIM, DDIM, 0, 0, (size_t)IDIM * DDIM, (size_t)DDIM * IDIM);

  gemm1_kernel<<<dim3(32, 32, NEXP), 256, 0, stream>>>(
      xb, wcat, gb, ub, lists, cnt, hbuf);
  gemm2_kernel<<<dim3(32, 8, NEXP), 256, 0, stream>>>(
      hbuf, downT, lists, cnt, cbuf);
  combine_kernel<<<T_TOK * DDIM / 8 / 256, 256, 0, stream>>>(cbuf, db, pexp, wts, out);
}